// Round 6
// baseline (6181.564 us; speedup 1.0000x reference)
//
#include <hip/hip_runtime.h>
#include <hip/hip_cooperative_groups.h>
#include <cmath>

namespace cg = cooperative_groups;

#define T_STEPS 512
#define NBLK 256
#define FLAG_STRIDE 16  // 64B-padded flag slots

typedef _Float16 h8 __attribute__((ext_vector_type(8)));
typedef float f4 __attribute__((ext_vector_type(4)));

// ---------------- pack P = emb @ [Wx interleaved] + bias : [513][4096] fp32 (exact input path)
__global__ void pack_P(const float* __restrict__ emb,
                       const float* __restrict__ Wgx, const float* __restrict__ Wix,
                       const float* __restrict__ Wfx, const float* __restrict__ Wox,
                       const float* __restrict__ bg, const float* __restrict__ bi,
                       const float* __restrict__ bf_, const float* __restrict__ bo,
                       float* __restrict__ P) {
  __shared__ float es[8][512];
  const int vg = blockIdx.x;   // 0..64
  const int st = blockIdx.y;   // 0..15
  const int tid = threadIdx.x;
  for (int i = tid; i < 8 * 512; i += 256) {
    int vv = i >> 9, k = i & 511;
    int v = vg * 8 + vv;
    es[vv][k] = (v < 513) ? emb[v * 512 + k] : 0.f;
  }
  __syncthreads();
  const int c = st * 256 + tid;
  const int gate = c & 3, unit = c >> 2;
  const float* W = gate == 0 ? Wgx : gate == 1 ? Wix : gate == 2 ? Wfx : Wox;
  const float* bias = gate == 0 ? bg : gate == 1 ? bi : gate == 2 ? bf_ : bo;
  float acc[8];
  const float bv = bias[unit];
#pragma unroll
  for (int vv = 0; vv < 8; vv++) acc[vv] = bv;
  for (int k = 0; k < 512; k++) {
    float w = W[k * 1024 + unit];
#pragma unroll
    for (int vv = 0; vv < 8; vv++) acc[vv] += es[vv][k] * w;
  }
#pragma unroll
  for (int vv = 0; vv < 8; vv++) {
    int v = vg * 8 + vv;
    if (v < 513) P[(size_t)v * 4096 + c] = acc[vv];
  }
}

// ---------------- pack Wt[c][k] = W_{gate(c)}h[k][unit(c)] as fp16
__global__ void pack_Wt(const float* __restrict__ Wgh, const float* __restrict__ Wih,
                        const float* __restrict__ Wfh, const float* __restrict__ Woh,
                        _Float16* __restrict__ Wt) {
  const int c = blockIdx.x;
  const int gate = c & 3, unit = c >> 2;
  const float* W = gate == 0 ? Wgh : gate == 1 ? Wih : gate == 2 ? Wfh : Woh;
  for (int k = threadIdx.x; k < 1024; k += 256)
    Wt[(size_t)c * 1024 + k] = (_Float16)W[k * 1024 + unit];
}

// ---------------- persistent LSTM: 256 blocks x 512 threads (1 block/CU).
// Block owns 16 gate-cols (4 hidden units). Wave w holds B for K-slice
// [128w,128w+128) in 16 VGPRs (no per-step W traffic at all). Per step:
// 32 coalesced A-loads + 32 MFMA -> fp32 partials in LDS -> 8-way reduce +
// exact-P (LDS-resident) + gates -> packed 8B sc1 h-store. Sync = R2/R5
// protocol: sc1 stores -> syncthreads (vmcnt drain) -> relaxed flag -> spin ->
// syncthreads -> wave0 agent-acquire fence -> syncthreads.
__launch_bounds__(512)
__global__ void lstm_step_all(const int* __restrict__ x,
                              const float* __restrict__ P,
                              const _Float16* __restrict__ Wt,
                              _Float16* __restrict__ hbuf,
                              float* __restrict__ h32,
                              const float* __restrict__ h_init,
                              const float* __restrict__ c_init,
                              unsigned int* __restrict__ flags) {
  cg::grid_group grid = cg::this_grid();
  __shared__ float partial[8][128][16];   // 64 KB fp32 split-K partials
  __shared__ float Plds[513 * 20];        // 41 KB: P slice, row stride 20 (16B-aligned)
  __shared__ unsigned short hst[128][4];  // 1 KB h-pack staging
  __shared__ int xs2[2][128];
  const int tid = threadIdx.x;
  const int blk = blockIdx.x;  // 0..255
  const int lane = tid & 63;
  const int wid = tid >> 6;    // 0..7 = K-slice owner
  const int colbase = blk * 16;

  if (tid == 0)
    __hip_atomic_store(&flags[blk * FLAG_STRIDE], 0u, __ATOMIC_RELAXED, __HIP_MEMORY_SCOPE_AGENT);

  const int l15 = lane & 15;
  const int kg = (lane >> 4) * 8;

  // B fragments: 16 cols x 128 K per wave, resident in VGPRs for all 512 steps
  h8 bfr[4];
#pragma unroll
  for (int s = 0; s < 4; s++)
    bfr[s] = *(const h8*)&Wt[(size_t)(colbase + l15) * 1024 + wid * 128 + s * 32 + kg];

  // stage P slice into LDS: Plds[v*20 + c] = P[v][colbase + c], c in [0,16)
  for (int i = tid; i < 513 * 4; i += 512) {
    int v = i >> 2, q = i & 3;
    *(f4*)&Plds[v * 20 + q * 4] = *(const f4*)&P[(size_t)v * 4096 + colbase + q * 4];
  }

  // per-thread state: thread owns (row = tid>>2, local unit u = tid&3)
  const int urow = tid >> 2;
  const int uu = tid & 3;
  const int gu = blk * 4 + uu;  // global hidden unit
  float cst = c_init[gu];
  if (tid < 128) {
    union { _Float16 h[4]; unsigned long long u; } pk;
#pragma unroll
    for (int u = 0; u < 4; u++) pk.h[u] = (_Float16)h_init[blk * 4 + u];
    *(unsigned long long*)&hbuf[tid * 1024 + blk * 4] = pk.u;  // buffer 0
  }
  if (tid < 128) xs2[0][tid] = x[tid * 513 + 0];
  grid.sync();  // once at init: covers h0, flags, Wt/P reads

#define LOADA(DST, S)                                                  \
  _Pragma("unroll") for (int r = 0; r < 8; ++r)                        \
      DST[r] = *(const h8*)(hcw + r * 16384 + (S) * 32);

#define MFMAS(SRC, S)                                                  \
  _Pragma("unroll") for (int r = 0; r < 8; ++r)                        \
      acc[r] = __builtin_amdgcn_mfma_f32_16x16x32_f16(SRC[r], bfr[S], acc[r], 0, 0, 0);

  for (int t = 0; t < T_STEPS; t++) {
    const _Float16* hc = hbuf + (t & 1) * (128 * 1024);
    _Float16* hn = hbuf + ((t + 1) & 1) * (128 * 1024);

    // ---- MFMA phase: this wave covers all 128 rows x 16 cols, K in [128w,128w+128)
    const _Float16* hcw = hc + (size_t)l15 * 1024 + wid * 128 + kg;
    f4 acc[8];
#pragma unroll
    for (int r = 0; r < 8; r++) acc[r] = (f4){0.f, 0.f, 0.f, 0.f};
    h8 aa[8], ab[8];
    LOADA(aa, 0);
    LOADA(ab, 1);
    MFMAS(aa, 0);
    LOADA(aa, 2);
    MFMAS(ab, 1);
    LOADA(ab, 3);
    MFMAS(aa, 2);
    MFMAS(ab, 3);

    // partial[w][row][col] = acc  (row = 16r + (lane>>4)*4 + i, col = l15)
#pragma unroll
    for (int r = 0; r < 8; r++) {
#pragma unroll
      for (int i = 0; i < 4; i++)
        partial[wid][r * 16 + (lane >> 4) * 4 + i][l15] = acc[r][i];
    }
    __syncthreads();

    // ---- reduce + gates: thread (row=tid>>2, unit uu=tid&3)
    {
      int xrow = xs2[t & 1][urow];
      f4 s = *(const f4*)&Plds[xrow * 20 + uu * 4];  // exact input-path preact
#pragma unroll
      for (int w = 0; w < 8; w++) s += *(const f4*)&partial[w][urow][uu * 4];
      float g = tanhf(s[0]);
      float i = 1.f / (1.f + expf(-s[1]));
      float f = 1.f / (1.f + expf(-s[2]));
      float o = 1.f / (1.f + expf(-s[3]));
      cst = g * i + cst * f;
      float hv = tanhf(cst) * o;
      union { _Float16 hh; unsigned short us; } cv;
      cv.hh = (_Float16)hv;
      hst[urow][uu] = cv.us;
      if (t == T_STEPS - 1) h32[urow * 1024 + gu] = hv;
    }
    if (t == T_STEPS - 1) break;
    __syncthreads();

    // ---- pack + publish: tid<128 stores packed 8B h (sc1); tid 128..255 prefetch x
    if (tid < 128) {
      unsigned long long pv = *(const unsigned long long*)&hst[tid][0];
      __hip_atomic_store((unsigned long long*)&hn[tid * 1024 + blk * 4], pv,
                         __ATOMIC_RELAXED, __HIP_MEMORY_SCOPE_AGENT);
    } else if (tid < 256) {
      xs2[(t + 1) & 1][tid - 128] = x[(tid - 128) * 513 + (t + 1)];
    }
    __syncthreads();  // vmcnt drain: all sc1 stores ack'd at LLC before publish
    if (tid == 0)
      __hip_atomic_store(&flags[blk * FLAG_STRIDE], (unsigned int)(t + 1),
                         __ATOMIC_RELAXED, __HIP_MEMORY_SCOPE_AGENT);
    if (tid < NBLK) {
      while (__hip_atomic_load(&flags[tid * FLAG_STRIDE], __ATOMIC_RELAXED,
                               __HIP_MEMORY_SCOPE_AGENT) < (unsigned int)(t + 1)) {
        __builtin_amdgcn_s_sleep(1);
      }
    }
    __syncthreads();
    // acquire once per block (wave 0): invalidate stale hbuf lines in L1/L2
    if (wid == 0) __builtin_amdgcn_fence(__ATOMIC_ACQUIRE, "agent");
    __syncthreads();
  }
}

// ---------------- final projection p = h_T @ W_ph + b_p (fp32)
__global__ void proj(const float* __restrict__ h32, const float* __restrict__ Wph,
                     const float* __restrict__ bp, float* __restrict__ logits) {
  const int b = blockIdx.x >> 1;
  const int cc = (blockIdx.x & 1) * 256 + threadIdx.x;
  const float* hrow = h32 + b * 1024;
  float acc = bp[cc];
#pragma unroll 4
  for (int k = 0; k < 1024; k++) acc += hrow[k] * Wph[k * 512 + cc];
  logits[b * 512 + cc] = acc;
}

// ---------------- row-wise log_softmax
__global__ void lsm(const float* __restrict__ logits, float* __restrict__ out) {
  const int b = blockIdx.x;
  const int tid = threadIdx.x;
  __shared__ float sm[4];
  __shared__ float se[4];
  float v0 = logits[b * 512 + tid];
  float v1 = logits[b * 512 + 256 + tid];
  float m = fmaxf(v0, v1);
  for (int o = 1; o < 64; o <<= 1) m = fmaxf(m, __shfl_xor(m, o, 64));
  if ((tid & 63) == 0) sm[tid >> 6] = m;
  __syncthreads();
  m = fmaxf(fmaxf(sm[0], sm[1]), fmaxf(sm[2], sm[3]));
  float e = expf(v0 - m) + expf(v1 - m);
  for (int o = 1; o < 64; o <<= 1) e += __shfl_xor(e, o, 64);
  if ((tid & 63) == 0) se[tid >> 6] = e;
  __syncthreads();
  float ls = logf(se[0] + se[1] + se[2] + se[3]) + m;
  out[b * 512 + tid] = v0 - ls;
  out[b * 512 + 256 + tid] = v1 - ls;
}

extern "C" void kernel_launch(void* const* d_in, const int* in_sizes, int n_in,
                              void* d_out, int out_size, void* d_ws, size_t ws_size,
                              hipStream_t stream) {
  const int* x = (const int*)d_in[0];
  const float* emb = (const float*)d_in[1];
  const float* Wgx = (const float*)d_in[2];
  const float* Wgh = (const float*)d_in[3];
  const float* bg = (const float*)d_in[4];
  const float* Wix = (const float*)d_in[5];
  const float* Wih = (const float*)d_in[6];
  const float* bi = (const float*)d_in[7];
  const float* Wfx = (const float*)d_in[8];
  const float* Wfh = (const float*)d_in[9];
  const float* bf = (const float*)d_in[10];
  const float* Wox = (const float*)d_in[11];
  const float* Woh = (const float*)d_in[12];
  const float* bo = (const float*)d_in[13];
  const float* Wph = (const float*)d_in[14];
  const float* bp = (const float*)d_in[15];
  const float* h_init = (const float*)d_in[16];
  const float* c_init = (const float*)d_in[17];

  char* ws = (char*)d_ws;
  float* P = (float*)ws;                                   // 520*4096*4   = 8,519,680
  unsigned int* flags = (unsigned int*)(ws + (size_t)513 * 4096 * 4);  // P pad rows (16 KB)
  _Float16* Wt = (_Float16*)(ws + 8519680);                // 4096*1024*2  = 8,388,608
  _Float16* hbuf = (_Float16*)(ws + 8519680 + 8388608);    // 2*128*1024*2 = 524,288
  float* h32 = (float*)(ws + 8519680 + 8388608 + 524288);  // 128*1024*4   = 524,288
  float* logits = (float*)(ws + 8519680 + 8388608 + 524288 + 524288);  // 128*512*4

  pack_P<<<dim3(65, 16), 256, 0, stream>>>(emb, Wgx, Wix, Wfx, Wox, bg, bi, bf, bo, P);
  pack_Wt<<<4096, 256, 0, stream>>>(Wgh, Wih, Wfh, Woh, Wt);

  void* args[] = {(void*)&x, (void*)&P, (void*)&Wt, (void*)&hbuf,
                  (void*)&h32, (void*)&h_init, (void*)&c_init, (void*)&flags};
  hipLaunchCooperativeKernel((void*)lstm_step_all, dim3(NBLK), dim3(512), args, 0, stream);

  proj<<<256, 256, 0, stream>>>(h32, Wph, bp, logits);
  lsm<<<128, 256, 0, stream>>>(logits, (float*)d_out);
}

// Round 7
// 2835.245 us; speedup vs baseline: 2.1803x; 2.1803x over previous
//
#include <hip/hip_runtime.h>
#include <hip/hip_cooperative_groups.h>
#include <cmath>

namespace cg = cooperative_groups;

#define T_STEPS 512
#define NBLK 256
#define NGRP 8
#define CNT_STRIDE 16  // 64B-padded counter slots

typedef _Float16 h8 __attribute__((ext_vector_type(8)));
typedef float f4 __attribute__((ext_vector_type(4)));
typedef unsigned long long ull_t;

// ---------------- pack P = emb @ [Wx interleaved] + bias : [513][4096] fp32 (exact input path)
__global__ void pack_P(const float* __restrict__ emb,
                       const float* __restrict__ Wgx, const float* __restrict__ Wix,
                       const float* __restrict__ Wfx, const float* __restrict__ Wox,
                       const float* __restrict__ bg, const float* __restrict__ bi,
                       const float* __restrict__ bf_, const float* __restrict__ bo,
                       float* __restrict__ P) {
  __shared__ float es[8][512];
  const int vg = blockIdx.x;   // 0..64
  const int st = blockIdx.y;   // 0..15
  const int tid = threadIdx.x;
  for (int i = tid; i < 8 * 512; i += 256) {
    int vv = i >> 9, k = i & 511;
    int v = vg * 8 + vv;
    es[vv][k] = (v < 513) ? emb[v * 512 + k] : 0.f;
  }
  __syncthreads();
  const int c = st * 256 + tid;
  const int gate = c & 3, unit = c >> 2;
  const float* W = gate == 0 ? Wgx : gate == 1 ? Wix : gate == 2 ? Wfx : Wox;
  const float* bias = gate == 0 ? bg : gate == 1 ? bi : gate == 2 ? bf_ : bo;
  float acc[8];
  const float bv = bias[unit];
#pragma unroll
  for (int vv = 0; vv < 8; vv++) acc[vv] = bv;
  for (int k = 0; k < 512; k++) {
    float w = W[k * 1024 + unit];
#pragma unroll
    for (int vv = 0; vv < 8; vv++) acc[vv] += es[vv][k] * w;
  }
#pragma unroll
  for (int vv = 0; vv < 8; vv++) {
    int v = vg * 8 + vv;
    if (v < 513) P[(size_t)v * 4096 + c] = acc[vv];
  }
}

// ---------------- pack Wt[c][k] = W_{gate(c)}h[k][unit(c)] as fp16
__global__ void pack_Wt(const float* __restrict__ Wgh, const float* __restrict__ Wih,
                        const float* __restrict__ Wfh, const float* __restrict__ Woh,
                        _Float16* __restrict__ Wt) {
  const int c = blockIdx.x;
  const int gate = c & 3, unit = c >> 2;
  const float* W = gate == 0 ? Wgh : gate == 1 ? Wih : gate == 2 ? Wfh : Woh;
  for (int k = threadIdx.x; k < 1024; k += 256)
    Wt[(size_t)c * 1024 + k] = (_Float16)W[k * 1024 + unit];
}

// ---------------- persistent LSTM: 8 INDEPENDENT row-groups of 16 batch rows.
// Group g = blk&7 (32 blocks, XCD-co-located by round-robin placement); block
// sub = blk>>3 owns gate-cols [128*sub,128*sub+128) = hidden units [32*sub,+32)
// for rows [16g,16g+16). Wave w holds its 16 cols' FULL-K B in 128 VGPRs (W never
// re-read after init). Per step: stage 32KB A to LDS -> 32 MFMA/wave (4 acc
// chains) -> fp32 pre to LDS -> 512-way gate phase -> packed 8B sc1 h-stores ->
// drain -> per-group counter atomicAdd -> spin (group-local) -> agent-acquire.
__launch_bounds__(512, 2)
__global__ void lstm_step_all(const int* __restrict__ x,
                              const float* __restrict__ P,
                              const _Float16* __restrict__ Wt,
                              _Float16* __restrict__ hbuf,
                              float* __restrict__ h32,
                              const float* __restrict__ h_init,
                              const float* __restrict__ c_init,
                              unsigned int* __restrict__ cnt) {
  cg::grid_group grid = cg::this_grid();
  __shared__ _Float16 alds[16 * 1024];   // 32 KB staged A (granule-XOR swizzled)
  __shared__ float pre[16 * 132];        // 8.25 KB fp32 pre-activations
  __shared__ unsigned short hst[16][32]; // 1 KB packed h staging
  __shared__ int xs2[2][16];
  const int tid = threadIdx.x;
  const int blk = blockIdx.x;
  const int grp = blk & 7;      // group == XCD (blk%8 round-robin placement)
  const int sub = blk >> 3;     // 0..31 col-partition
  const int lane = tid & 63;
  const int wid = tid >> 6;
  const int l15 = lane & 15;
  const int gg = lane >> 4;
  const int kg = gg * 8;
  const int colbase = sub * 128;  // gate-col base
  const int ubase = sub * 32;     // hidden-unit base
  const int rowbase = grp * 16;   // batch-row base

  if (blk < NGRP && tid == 0)
    __hip_atomic_store(&cnt[blk * CNT_STRIDE], 0u, __ATOMIC_RELAXED, __HIP_MEMORY_SCOPE_AGENT);

  // B resident in VGPRs: wave w covers cols colbase + w*16 .. +16, all K
  h8 bfr[32];
  {
    const _Float16* wp = Wt + (size_t)(colbase + wid * 16 + l15) * 1024 + kg;
#pragma unroll
    for (int s = 0; s < 32; s++) bfr[s] = *(const h8*)(wp + s * 32);
  }

  // init h0 slice (this block's rows x units) into buffer 0
  if (tid < 128) {
    int row = tid >> 3, q = tid & 7;
    union { _Float16 h[4]; ull_t u; } pk;
#pragma unroll
    for (int u = 0; u < 4; u++) pk.h[u] = (_Float16)h_init[ubase + q * 4 + u];
    *(ull_t*)&hbuf[(size_t)(rowbase + row) * 1024 + ubase + q * 4] = pk.u;
  }
  if (tid < 16) xs2[0][tid] = x[(rowbase + tid) * 513];
  // gate-phase identity: row = tid>>5, unit = tid&31 (persistent c state)
  const int grow = tid >> 5;
  const int gu = tid & 31;
  float cst = c_init[ubase + gu];
  grid.sync();  // once at init: covers h0, counters, Wt/P

  for (int t = 0; t < T_STEPS; t++) {
    const _Float16* hc = hbuf + (t & 1) * (128 * 1024);
    _Float16* hn = hbuf + ((t + 1) & 1) * (128 * 1024);

    // exact-P gather issued early (LLC latency hides under A-stage + MFMA)
    const float* prow = P + (size_t)xs2[t & 1][grow] * 4096 + colbase + gu * 4;
    f4 pv = *(const f4*)prow;

    // stage A: 16 rows x 2KB, coalesced global -> swizzled LDS
#pragma unroll
    for (int r = 0; r < 4; r++) {
      int idx = r * 512 + tid;
      int ar = idx >> 7, g = idx & 127;
      h8 v = *(const h8*)&hc[(size_t)(rowbase + ar) * 1024 + g * 8];
      *(h8*)&alds[ar * 1024 + ((g ^ (ar & 7)) * 8)] = v;
    }
    __syncthreads();

    // MFMA: 16 rows x 16 cols x K=1024, B from regs, 4 independent acc chains
    f4 ac0 = {0.f, 0.f, 0.f, 0.f}, ac1 = ac0, ac2 = ac0, ac3 = ac0;
#pragma unroll
    for (int s = 0; s < 32; s++) {
      int g = s * 4 + gg;
      h8 a = *(const h8*)&alds[l15 * 1024 + ((g ^ (l15 & 7)) * 8)];
      if ((s & 3) == 0) ac0 = __builtin_amdgcn_mfma_f32_16x16x32_f16(a, bfr[s], ac0, 0, 0, 0);
      else if ((s & 3) == 1) ac1 = __builtin_amdgcn_mfma_f32_16x16x32_f16(a, bfr[s], ac1, 0, 0, 0);
      else if ((s & 3) == 2) ac2 = __builtin_amdgcn_mfma_f32_16x16x32_f16(a, bfr[s], ac2, 0, 0, 0);
      else ac3 = __builtin_amdgcn_mfma_f32_16x16x32_f16(a, bfr[s], ac3, 0, 0, 0);
    }
    f4 acc = (ac0 + ac1) + (ac2 + ac3);
#pragma unroll
    for (int i = 0; i < 4; i++)
      pre[(gg * 4 + i) * 132 + wid * 16 + l15] = acc[i];
    __syncthreads();

    // gate phase: thread (grow, gu), full fp32
    {
      f4 q = *(const f4*)&pre[grow * 132 + gu * 4];
      q += pv;
      float g_ = tanhf(q[0]);
      float i_ = 1.f / (1.f + expf(-q[1]));
      float f_ = 1.f / (1.f + expf(-q[2]));
      float o_ = 1.f / (1.f + expf(-q[3]));
      cst = g_ * i_ + cst * f_;
      float hv = tanhf(cst) * o_;
      union { _Float16 hh; unsigned short us; } cv;
      cv.hh = (_Float16)hv;
      hst[grow][gu] = cv.us;
      if (t == T_STEPS - 1) h32[(size_t)(rowbase + grow) * 1024 + ubase + gu] = hv;
    }
    if (tid >= 496) xs2[(t + 1) & 1][tid - 496] = x[(rowbase + tid - 496) * 513 + (t + 1)];
    if (t == T_STEPS - 1) break;
    __syncthreads();

    // publish: packed 8B sc1 stores (16 rows x 64 B)
    if (tid < 128) {
      int row = tid >> 3, q8 = tid & 7;
      ull_t pv8 = *(const ull_t*)&hst[row][q8 * 4];
      __hip_atomic_store((ull_t*)&hn[(size_t)(rowbase + row) * 1024 + ubase + q8 * 4], pv8,
                         __ATOMIC_RELAXED, __HIP_MEMORY_SCOPE_AGENT);
    }
    __syncthreads();  // vmcnt drain: all sc1 stores ack'd at LLC before arrival
    if (tid == 0) {
      __hip_atomic_fetch_add(&cnt[grp * CNT_STRIDE], 1u,
                             __ATOMIC_RELAXED, __HIP_MEMORY_SCOPE_AGENT);
      while (__hip_atomic_load(&cnt[grp * CNT_STRIDE], __ATOMIC_RELAXED,
                               __HIP_MEMORY_SCOPE_AGENT) < 32u * (unsigned)(t + 1)) {
        __builtin_amdgcn_s_sleep(1);
      }
    }
    __syncthreads();
    // acquire once per block (wave 0): invalidate stale h lines in L1/L2
    if (wid == 0) __builtin_amdgcn_fence(__ATOMIC_ACQUIRE, "agent");
    __syncthreads();
  }
}

// ---------------- final projection p = h_T @ W_ph + b_p (fp32)
__global__ void proj(const float* __restrict__ h32, const float* __restrict__ Wph,
                     const float* __restrict__ bp, float* __restrict__ logits) {
  const int b = blockIdx.x >> 1;
  const int cc = (blockIdx.x & 1) * 256 + threadIdx.x;
  const float* hrow = h32 + b * 1024;
  float acc = bp[cc];
#pragma unroll 4
  for (int k = 0; k < 1024; k++) acc += hrow[k] * Wph[k * 512 + cc];
  logits[b * 512 + cc] = acc;
}

// ---------------- row-wise log_softmax
__global__ void lsm(const float* __restrict__ logits, float* __restrict__ out) {
  const int b = blockIdx.x;
  const int tid = threadIdx.x;
  __shared__ float sm[4];
  __shared__ float se[4];
  float v0 = logits[b * 512 + tid];
  float v1 = logits[b * 512 + 256 + tid];
  float m = fmaxf(v0, v1);
  for (int o = 1; o < 64; o <<= 1) m = fmaxf(m, __shfl_xor(m, o, 64));
  if ((tid & 63) == 0) sm[tid >> 6] = m;
  __syncthreads();
  m = fmaxf(fmaxf(sm[0], sm[1]), fmaxf(sm[2], sm[3]));
  float e = expf(v0 - m) + expf(v1 - m);
  for (int o = 1; o < 64; o <<= 1) e += __shfl_xor(e, o, 64);
  if ((tid & 63) == 0) se[tid >> 6] = e;
  __syncthreads();
  float ls = logf(se[0] + se[1] + se[2] + se[3]) + m;
  out[b * 512 + tid] = v0 - ls;
  out[b * 512 + 256 + tid] = v1 - ls;
}

extern "C" void kernel_launch(void* const* d_in, const int* in_sizes, int n_in,
                              void* d_out, int out_size, void* d_ws, size_t ws_size,
                              hipStream_t stream) {
  const int* x = (const int*)d_in[0];
  const float* emb = (const float*)d_in[1];
  const float* Wgx = (const float*)d_in[2];
  const float* Wgh = (const float*)d_in[3];
  const float* bg = (const float*)d_in[4];
  const float* Wix = (const float*)d_in[5];
  const float* Wih = (const float*)d_in[6];
  const float* bi = (const float*)d_in[7];
  const float* Wfx = (const float*)d_in[8];
  const float* Wfh = (const float*)d_in[9];
  const float* bf = (const float*)d_in[10];
  const float* Wox = (const float*)d_in[11];
  const float* Woh = (const float*)d_in[12];
  const float* bo = (const float*)d_in[13];
  const float* Wph = (const float*)d_in[14];
  const float* bp = (const float*)d_in[15];
  const float* h_init = (const float*)d_in[16];
  const float* c_init = (const float*)d_in[17];

  char* ws = (char*)d_ws;
  float* P = (float*)ws;                                   // 520*4096*4   = 8,519,680
  unsigned int* cnt = (unsigned int*)(ws + (size_t)513 * 4096 * 4);  // P pad rows
  _Float16* Wt = (_Float16*)(ws + 8519680);                // 4096*1024*2  = 8,388,608
  _Float16* hbuf = (_Float16*)(ws + 8519680 + 8388608);    // 2*128*1024*2 = 524,288
  float* h32 = (float*)(ws + 8519680 + 8388608 + 524288);  // 128*1024*4   = 524,288
  float* logits = (float*)(ws + 8519680 + 8388608 + 524288 + 524288);  // 128*512*4

  pack_P<<<dim3(65, 16), 256, 0, stream>>>(emb, Wgx, Wix, Wfx, Wox, bg, bi, bf, bo, P);
  pack_Wt<<<4096, 256, 0, stream>>>(Wgh, Wih, Wfh, Woh, Wt);

  void* args[] = {(void*)&x, (void*)&P, (void*)&Wt, (void*)&hbuf,
                  (void*)&h32, (void*)&h_init, (void*)&c_init, (void*)&cnt};
  hipLaunchCooperativeKernel((void*)lstm_step_all, dim3(NBLK), dim3(512), args, 0, stream);

  proj<<<256, 256, 0, stream>>>(h32, Wph, bp, logits);
  lsm<<<128, 256, 0, stream>>>(logits, (float*)d_out);
}

// Round 8
// 1923.596 us; speedup vs baseline: 3.2135x; 1.4739x over previous
//
#include <hip/hip_runtime.h>
#include <hip/hip_cooperative_groups.h>
#include <cmath>

namespace cg = cooperative_groups;

#define T_STEPS 512
#define NBLK 256
#define NGRP 8
#define CNT_STRIDE 16  // 64B-padded counter slots

typedef _Float16 h8 __attribute__((ext_vector_type(8)));
typedef float f4 __attribute__((ext_vector_type(4)));
typedef int i32x4 __attribute__((ext_vector_type(4)));
typedef unsigned long long ull_t;

__device__ __forceinline__ float sigm(float v) { return 1.f / (1.f + __expf(-v)); }
__device__ __forceinline__ float tanh_fast(float v) { return 1.f - 2.f / (__expf(2.f * v) + 1.f); }

// ---------------- pack P = emb @ [Wx interleaved] + bias : [513][4096] fp32 (exact input path)
__global__ void pack_P(const float* __restrict__ emb,
                       const float* __restrict__ Wgx, const float* __restrict__ Wix,
                       const float* __restrict__ Wfx, const float* __restrict__ Wox,
                       const float* __restrict__ bg, const float* __restrict__ bi,
                       const float* __restrict__ bf_, const float* __restrict__ bo,
                       float* __restrict__ P) {
  __shared__ float es[8][512];
  const int vg = blockIdx.x;   // 0..64
  const int st = blockIdx.y;   // 0..15
  const int tid = threadIdx.x;
  for (int i = tid; i < 8 * 512; i += 256) {
    int vv = i >> 9, k = i & 511;
    int v = vg * 8 + vv;
    es[vv][k] = (v < 513) ? emb[v * 512 + k] : 0.f;
  }
  __syncthreads();
  const int c = st * 256 + tid;
  const int gate = c & 3, unit = c >> 2;
  const float* W = gate == 0 ? Wgx : gate == 1 ? Wix : gate == 2 ? Wfx : Wox;
  const float* bias = gate == 0 ? bg : gate == 1 ? bi : gate == 2 ? bf_ : bo;
  float acc[8];
  const float bv = bias[unit];
#pragma unroll
  for (int vv = 0; vv < 8; vv++) acc[vv] = bv;
  for (int k = 0; k < 512; k++) {
    float w = W[k * 1024 + unit];
#pragma unroll
    for (int vv = 0; vv < 8; vv++) acc[vv] += es[vv][k] * w;
  }
#pragma unroll
  for (int vv = 0; vv < 8; vv++) {
    int v = vg * 8 + vv;
    if (v < 513) P[(size_t)v * 4096 + c] = acc[vv];
  }
}

// ---------------- pack Wt[c][k] = W_{gate(c)}h[k][unit(c)] as fp16
__global__ void pack_Wt(const float* __restrict__ Wgh, const float* __restrict__ Wih,
                        const float* __restrict__ Wfh, const float* __restrict__ Woh,
                        _Float16* __restrict__ Wt) {
  const int c = blockIdx.x;
  const int gate = c & 3, unit = c >> 2;
  const float* W = gate == 0 ? Wgh : gate == 1 ? Wih : gate == 2 ? Wfh : Woh;
  for (int k = threadIdx.x; k < 1024; k += 256)
    Wt[(size_t)c * 1024 + k] = (_Float16)W[k * 1024 + unit];
}

// ---------------- persistent LSTM: 8 independent row-groups of 16 batch rows.
// Group g = blk&7; block sub = blk>>3 owns hidden units [32*sub,+32) for rows
// [16g,16g+16). B fully VGPR-resident per wave. NO per-step cache fence:
// h-loads are direct-to-LLC (sc0 sc1) inline asm, so stale L1/L2 never seen;
// P/x stay warm in L2. Protocol: sc1 h-stores -> syncthreads (vmcnt drain) ->
// counter atomicAdd -> tid0 spin -> syncthreads -> coherent A-loads.
__launch_bounds__(512, 2)
__global__ void lstm_step_all(const int* __restrict__ x,
                              const float* __restrict__ P,
                              const _Float16* __restrict__ Wt,
                              _Float16* __restrict__ hbuf,
                              float* __restrict__ h32,
                              const float* __restrict__ h_init,
                              const float* __restrict__ c_init,
                              unsigned int* __restrict__ cnt) {
  cg::grid_group grid = cg::this_grid();
  __shared__ _Float16 alds[16 * 1024];   // 32 KB staged A (granule-XOR swizzled)
  __shared__ float pre[16 * 132];        // 8.25 KB fp32 pre-activations
  __shared__ unsigned short hst[16][32]; // 1 KB packed h staging
  __shared__ int xs2[2][16];
  const int tid = threadIdx.x;
  const int blk = blockIdx.x;
  const int grp = blk & 7;      // group (XCD-co-located by blk%8 round-robin)
  const int sub = blk >> 3;     // 0..31 col-partition
  const int lane = tid & 63;
  const int wid = tid >> 6;
  const int l15 = lane & 15;
  const int gg = lane >> 4;
  const int kg = gg * 8;
  const int colbase = sub * 128;  // gate-col base
  const int ubase = sub * 32;     // hidden-unit base
  const int rowbase = grp * 16;   // batch-row base

  if (blk < NGRP && tid == 0)
    __hip_atomic_store(&cnt[blk * CNT_STRIDE], 0u, __ATOMIC_RELAXED, __HIP_MEMORY_SCOPE_AGENT);

  // B resident in VGPRs: wave w covers cols colbase + w*16 .. +16, all K
  h8 bfr[32];
  {
    const _Float16* wp = Wt + (size_t)(colbase + wid * 16 + l15) * 1024 + kg;
#pragma unroll
    for (int s = 0; s < 32; s++) bfr[s] = *(const h8*)(wp + s * 32);
  }

  // init h0 slice (this block's rows x units) into buffer 0
  if (tid < 128) {
    int row = tid >> 3, q = tid & 7;
    union { _Float16 h[4]; ull_t u; } pk;
#pragma unroll
    for (int u = 0; u < 4; u++) pk.h[u] = (_Float16)h_init[ubase + q * 4 + u];
    *(ull_t*)&hbuf[(size_t)(rowbase + row) * 1024 + ubase + q * 4] = pk.u;
  }
  if (tid < 16) xs2[0][tid] = x[(rowbase + tid) * 513];
  // gate-phase identity: row = tid>>5, unit = tid&31 (persistent c state)
  const int grow = tid >> 5;
  const int gu = tid & 31;
  float cst = c_init[ubase + gu];
  grid.sync();  // once at init: covers h0, counters, Wt/P

  for (int t = 0; t < T_STEPS; t++) {
    const _Float16* hc = hbuf + (t & 1) * (128 * 1024);
    _Float16* hn = hbuf + ((t + 1) & 1) * (128 * 1024);

    // exact-P gather issued early (L2-warm; latency hides under A-load window)
    const float* prow = P + (size_t)xs2[t & 1][grow] * 4096 + colbase + gu * 4;
    f4 pv = *(const f4*)prow;

    // ---- A-stage: 16 rows x 2KB via direct-to-LLC loads (bypass stale L1/L2).
    // 128 consecutive threads read one row's contiguous 2KB -> fully coalesced.
    i32x4 av[4];
#pragma unroll
    for (int r = 0; r < 4; r++) {
      int idx = r * 512 + tid;
      int ar = idx >> 7, g = idx & 127;
      const _Float16* p = &hc[(size_t)(rowbase + ar) * 1024 + g * 8];
      asm volatile("global_load_dwordx4 %0, %1, off sc0 sc1"
                   : "=v"(av[r]) : "v"(p) : "memory");
    }
    asm volatile("s_waitcnt vmcnt(0)" ::: "memory");
    __builtin_amdgcn_sched_barrier(0);
#pragma unroll
    for (int r = 0; r < 4; r++) {
      int idx = r * 512 + tid;
      int ar = idx >> 7, g = idx & 127;
      *(i32x4*)&alds[ar * 1024 + ((g ^ (ar & 7)) * 8)] = av[r];
    }
    __syncthreads();

    // ---- MFMA: 16 rows x 16 cols x K=1024, B from regs, 4 acc chains
    f4 ac0 = {0.f, 0.f, 0.f, 0.f}, ac1 = ac0, ac2 = ac0, ac3 = ac0;
#pragma unroll
    for (int s = 0; s < 32; s++) {
      int g = s * 4 + gg;
      h8 a = *(const h8*)&alds[l15 * 1024 + ((g ^ (l15 & 7)) * 8)];
      if ((s & 3) == 0) ac0 = __builtin_amdgcn_mfma_f32_16x16x32_f16(a, bfr[s], ac0, 0, 0, 0);
      else if ((s & 3) == 1) ac1 = __builtin_amdgcn_mfma_f32_16x16x32_f16(a, bfr[s], ac1, 0, 0, 0);
      else if ((s & 3) == 2) ac2 = __builtin_amdgcn_mfma_f32_16x16x32_f16(a, bfr[s], ac2, 0, 0, 0);
      else ac3 = __builtin_amdgcn_mfma_f32_16x16x32_f16(a, bfr[s], ac3, 0, 0, 0);
    }
    f4 acc = (ac0 + ac1) + (ac2 + ac3);
#pragma unroll
    for (int i = 0; i < 4; i++)
      pre[(gg * 4 + i) * 132 + wid * 16 + l15] = acc[i];
    __syncthreads();

    // ---- gate phase: thread (grow, gu), full fp32
    {
      f4 q = *(const f4*)&pre[grow * 132 + gu * 4];
      q += pv;
      float g_ = tanh_fast(q[0]);
      float i_ = sigm(q[1]);
      float f_ = sigm(q[2]);
      float o_ = sigm(q[3]);
      cst = g_ * i_ + cst * f_;
      float hv = tanh_fast(cst) * o_;
      union { _Float16 hh; unsigned short us; } cv;
      cv.hh = (_Float16)hv;
      hst[grow][gu] = cv.us;
      if (t == T_STEPS - 1) h32[(size_t)(rowbase + grow) * 1024 + ubase + gu] = hv;
    }
    if (tid >= 496) xs2[(t + 1) & 1][tid - 496] = x[(rowbase + tid - 496) * 513 + (t + 1)];
    if (t == T_STEPS - 1) break;
    __syncthreads();

    // ---- publish: packed 8B sc1 stores (16 rows x 64 B per block)
    if (tid < 128) {
      int row = tid >> 3, q8 = tid & 7;
      ull_t pv8 = *(const ull_t*)&hst[row][q8 * 4];
      __hip_atomic_store((ull_t*)&hn[(size_t)(rowbase + row) * 1024 + ubase + q8 * 4], pv8,
                         __ATOMIC_RELAXED, __HIP_MEMORY_SCOPE_AGENT);
    }
    __syncthreads();  // vmcnt drain: all sc1 stores ack'd at LLC before arrival
    if (tid == 0) {
      __hip_atomic_fetch_add(&cnt[grp * CNT_STRIDE], 1u,
                             __ATOMIC_RELAXED, __HIP_MEMORY_SCOPE_AGENT);
      while (__hip_atomic_load(&cnt[grp * CNT_STRIDE], __ATOMIC_RELAXED,
                               __HIP_MEMORY_SCOPE_AGENT) < 32u * (unsigned)(t + 1)) {
        __builtin_amdgcn_s_sleep(1);
      }
    }
    __syncthreads();
    // no fence: next step's h reads are sc0/sc1 (coherent at LLC) by construction
  }
}

// ---------------- final projection p = h_T @ W_ph + b_p (fp32)
__global__ void proj(const float* __restrict__ h32, const float* __restrict__ Wph,
                     const float* __restrict__ bp, float* __restrict__ logits) {
  const int b = blockIdx.x >> 1;
  const int cc = (blockIdx.x & 1) * 256 + threadIdx.x;
  const float* hrow = h32 + b * 1024;
  float acc = bp[cc];
#pragma unroll 4
  for (int k = 0; k < 1024; k++) acc += hrow[k] * Wph[k * 512 + cc];
  logits[b * 512 + cc] = acc;
}

// ---------------- row-wise log_softmax
__global__ void lsm(const float* __restrict__ logits, float* __restrict__ out) {
  const int b = blockIdx.x;
  const int tid = threadIdx.x;
  __shared__ float sm[4];
  __shared__ float se[4];
  float v0 = logits[b * 512 + tid];
  float v1 = logits[b * 512 + 256 + tid];
  float m = fmaxf(v0, v1);
  for (int o = 1; o < 64; o <<= 1) m = fmaxf(m, __shfl_xor(m, o, 64));
  if ((tid & 63) == 0) sm[tid >> 6] = m;
  __syncthreads();
  m = fmaxf(fmaxf(sm[0], sm[1]), fmaxf(sm[2], sm[3]));
  float e = expf(v0 - m) + expf(v1 - m);
  for (int o = 1; o < 64; o <<= 1) e += __shfl_xor(e, o, 64);
  if ((tid & 63) == 0) se[tid >> 6] = e;
  __syncthreads();
  float ls = logf(se[0] + se[1] + se[2] + se[3]) + m;
  out[b * 512 + tid] = v0 - ls;
  out[b * 512 + 256 + tid] = v1 - ls;
}

extern "C" void kernel_launch(void* const* d_in, const int* in_sizes, int n_in,
                              void* d_out, int out_size, void* d_ws, size_t ws_size,
                              hipStream_t stream) {
  const int* x = (const int*)d_in[0];
  const float* emb = (const float*)d_in[1];
  const float* Wgx = (const float*)d_in[2];
  const float* Wgh = (const float*)d_in[3];
  const float* bg = (const float*)d_in[4];
  const float* Wix = (const float*)d_in[5];
  const float* Wih = (const float*)d_in[6];
  const float* bi = (const float*)d_in[7];
  const float* Wfx = (const float*)d_in[8];
  const float* Wfh = (const float*)d_in[9];
  const float* bf = (const float*)d_in[10];
  const float* Wox = (const float*)d_in[11];
  const float* Woh = (const float*)d_in[12];
  const float* bo = (const float*)d_in[13];
  const float* Wph = (const float*)d_in[14];
  const float* bp = (const float*)d_in[15];
  const float* h_init = (const float*)d_in[16];
  const float* c_init = (const float*)d_in[17];

  char* ws = (char*)d_ws;
  float* P = (float*)ws;                                   // 520*4096*4   = 8,519,680
  unsigned int* cnt = (unsigned int*)(ws + (size_t)513 * 4096 * 4);  // P pad rows
  _Float16* Wt = (_Float16*)(ws + 8519680);                // 4096*1024*2  = 8,388,608
  _Float16* hbuf = (_Float16*)(ws + 8519680 + 8388608);    // 2*128*1024*2 = 524,288
  float* h32 = (float*)(ws + 8519680 + 8388608 + 524288);  // 128*1024*4   = 524,288
  float* logits = (float*)(ws + 8519680 + 8388608 + 524288 + 524288);  // 128*512*4

  pack_P<<<dim3(65, 16), 256, 0, stream>>>(emb, Wgx, Wix, Wfx, Wox, bg, bi, bf, bo, P);
  pack_Wt<<<4096, 256, 0, stream>>>(Wgh, Wih, Wfh, Woh, Wt);

  void* args[] = {(void*)&x, (void*)&P, (void*)&Wt, (void*)&hbuf,
                  (void*)&h32, (void*)&h_init, (void*)&c_init, (void*)&cnt};
  hipLaunchCooperativeKernel((void*)lstm_step_all, dim3(NBLK), dim3(512), args, 0, stream);

  proj<<<256, 256, 0, stream>>>(h32, Wph, bp, logits);
  lsm<<<128, 256, 0, stream>>>(logits, (float*)d_out);
}